// Round 12
// baseline (164.873 us; speedup 1.0000x reference)
//
#include <hip/hip_runtime.h>

// (B,C,L,H,W) = (4,64,16,32,32), K=1024, D=C=64
constexpr int Cc   = 64;
constexpr int Kc   = 1024;
constexpr int Dc   = 64;
constexpr int LHWc = 16 * 32 * 32;        // 16384
constexpr int Nc   = 4 * LHWc;            // 65536 vectors
constexpr int QSIZE    = 4 * Cc * LHWc;   // 4194304
constexpr int OFF_LOSS = QSIZE;           // 4194304
constexpr int OFF_IDX  = QSIZE + 1;       // 4194305

constexpr int BLK_ROWS = 256;             // rows per block (16 MFMA tiles)
constexpr int NW       = 8;               // waves per block (512 threads)
constexpr int XPAD     = 65;              // +1 pad: row stride ≡ 1 bank

typedef __attribute__((ext_vector_type(8))) short short8;   // 8 x bf16 bits
typedef __attribute__((ext_vector_type(4))) float f32x4;

static __device__ __forceinline__ unsigned short f2bf(float f) {
    unsigned u = __float_as_uint(f);
    u += 0x7FFFu + ((u >> 16) & 1u);      // RNE (finite data only)
    return (unsigned short)(u >> 16);
}
static __device__ __forceinline__ float bf2f(unsigned short h) {
    return __uint_as_float(((unsigned)h) << 16);
}

__global__ void vq_zero(float* __restrict__ out) {
    out[OFF_LOSS] = 0.0f;
}

// r5 shape (proven fastest: 256 rows / 16 1-tile iters / 8 waves x 128 codes /
// grid 256) with: prep fused in-block (A-frags + exact c2 from f32 codebook),
// accumulator seeded with c2n = -0.5*(c2+0.25) (score = dot + c2n, maximize),
// 4 independent per-r top-2 chains (dep depth 32 -> 8), XPAD 65.
// Final selection: exact recheck on the REFERENCE GRID d2 = fl(fma(-2,a,x2)+c2),
// f32-bit compare, lowest-k ties (r10 lesson: d2's k-part is quantized to
// ulp(x2+c2≈64)=7.6e-6, ~0.2% of rows coarse-tie, reference resolves by low k).
__global__ __launch_bounds__(512)
__attribute__((amdgpu_waves_per_eu(2, 2))) void vq_main(
    const float* __restrict__ in, const float* __restrict__ codebook,
    float* __restrict__ out)
{
    __shared__ float    xs[BLK_ROWS][XPAD];    // 66560 B
    __shared__ short8   xfh[2048];             // 32768 B: X frags hi
    __shared__ short8   xfl[2048];             // 32768 B: X frags lo
    __shared__ float    c2s[Kc];               //  4096 B: exact ||c||^2
    __shared__ float    xs2[BLK_ROWS];         //  1024 B
    __shared__ float    cV1[NW][BLK_ROWS];     //  8192 B
    __shared__ float    cV2[NW][BLK_ROWS];     //  8192 B
    __shared__ unsigned cK [NW][BLK_ROWS];     //  8192 B
    __shared__ unsigned kws[BLK_ROWS];         //  1024 B  (total 162816 B)

    const int tid  = threadIdx.x;
    const int lane = tid & 63;
    const int w    = __builtin_amdgcn_readfirstlane(tid >> 6);  // 0..7
    const int col  = lane & 15;
    const int g    = lane >> 4;

    const int bq = blockIdx.x >> 6;                    // batch (64 blk/batch)
    const int p0 = (blockIdx.x & 63) * BLK_ROWS;       // LHW offset
    const size_t inBase = (size_t)bq * (Cc * LHWc) + p0;

    // ---- stage X[256 rows][64 d] into LDS (coalesced) ----
#pragma unroll
    for (int i = 0; i < 32; ++i) {
        int idx = i * 512 + tid;
        int d = idx >> 8, row = idx & 255;
        xs[row][d] = in[inBase + (size_t)d * LHWc + row];
    }

    // ---- exact c2 chains, 2 codes/thread -> LDS ----
#pragma unroll
    for (int j = 0; j < 2; ++j) {
        const int k = tid + j * 512;
        const float* c = codebook + (size_t)k * Dc;
        float s = 0.f;
#pragma unroll
        for (int d = 0; d < Dc; ++d) s = __builtin_fmaf(c[d], c[d], s);
        c2s[k] = s;
    }

    // ---- this wave's 128 codes: bf16 hi/lo A-fragments from f32 codebook ----
    short8 Ah[8][2], Al[8][2];
#pragma unroll
    for (int ct = 0; ct < 8; ++ct) {
        const float* cr = codebook + (size_t)(w * 128 + ct * 16 + col) * Dc + g * 8;
#pragma unroll
        for (int kt = 0; kt < 2; ++kt) {
            f32x4 v0 = *(const f32x4*)(cr + kt * 32);
            f32x4 v1 = *(const f32x4*)(cr + kt * 32 + 4);
            short8 h8, l8;
#pragma unroll
            for (int e = 0; e < 4; ++e) {
                unsigned short ha = f2bf(v0[e]);
                h8[e]     = (short)ha;
                l8[e]     = (short)f2bf(v0[e] - bf2f(ha));
                unsigned short hb = f2bf(v1[e]);
                h8[4 + e] = (short)hb;
                l8[4 + e] = (short)f2bf(v1[e] - bf2f(hb));
            }
            Ah[ct][kt] = h8; Al[ct][kt] = l8;
        }
    }
    __syncthreads();

    // ---- x2 (exact ascending chain, recheck only) ----
    if (tid < BLK_ROWS) {
        float s = 0.f;
#pragma unroll
        for (int d = 0; d < Dc; ++d) s = __builtin_fmaf(xs[tid][d], xs[tid][d], s);
        xs2[tid] = s;
    }

    // ---- X fragments (bf16 hi/lo) from xs -> LDS ----
#pragma unroll
    for (int j = 0; j < 4; ++j) {
        const int c  = tid + j * 512;          // chunk = t*128 + kt*64 + g*16 + cl
        const int t  = c >> 7;
        const int kt = (c >> 6) & 1;
        const int l  = c & 63;
        const int row = t * 16 + (l & 15);
        const int d0  = kt * 32 + (l >> 4) * 8;
        f32x4 v0 = *(const f32x4*)&xs[row][d0];
        f32x4 v1 = *(const f32x4*)&xs[row][d0 + 4];
        short8 h8, l8;
#pragma unroll
        for (int e = 0; e < 4; ++e) {
            unsigned short ha = f2bf(v0[e]);
            h8[e]     = (short)ha;
            l8[e]     = (short)f2bf(v0[e] - bf2f(ha));
            unsigned short hb = f2bf(v1[e]);
            h8[4 + e] = (short)hb;
            l8[4 + e] = (short)f2bf(v1[e] - bf2f(hb));
        }
        xfh[c] = h8; xfl[c] = l8;
    }

    // ---- seeds: c2n = -0.5*(c2+0.25) for this thread's 32 codes ----
    f32x4 seed[8];
#pragma unroll
    for (int ct = 0; ct < 8; ++ct) {
        f32x4 cv = *(const f32x4*)&c2s[w * 128 + ct * 16 + g * 4];
#pragma unroll
        for (int e = 0; e < 4; ++e) seed[ct][e] = -0.5f * (cv[e] + 0.25f);
    }
    __syncthreads();

    const int kb = w * 128 + g * 4;            // + ct*16 + r at use

    // ---- main loop: 16 X-tiles, codes stay in registers ----
#pragma unroll 1
    for (int t = 0; t < 16; ++t) {
        const short8 xh0 = xfh[t * 128 + lane];
        const short8 xh1 = xfh[t * 128 + 64 + lane];
        const short8 xl0 = xfl[t * 128 + lane];
        const short8 xl1 = xfl[t * 128 + 64 + lane];

        float bV[4], sV[4];
        int   bK[4], sK[4];
#pragma unroll
        for (int r = 0; r < 4; ++r) {
            bV[r] = -3.4e38f; sV[r] = -3.4e38f; bK[r] = 0; sK[r] = 0;
        }

#pragma unroll
        for (int ct = 0; ct < 8; ++ct) {
            f32x4 acc = seed[ct];
            // split-3 dot: hh + hl + lh (ll ~1e-10, covered by exact recheck)
            acc = __builtin_amdgcn_mfma_f32_16x16x32_bf16(Ah[ct][0], xh0, acc, 0, 0, 0);
            acc = __builtin_amdgcn_mfma_f32_16x16x32_bf16(Ah[ct][1], xh1, acc, 0, 0, 0);
            acc = __builtin_amdgcn_mfma_f32_16x16x32_bf16(Ah[ct][0], xl0, acc, 0, 0, 0);
            acc = __builtin_amdgcn_mfma_f32_16x16x32_bf16(Ah[ct][1], xl1, acc, 0, 0, 0);
            acc = __builtin_amdgcn_mfma_f32_16x16x32_bf16(Al[ct][0], xh0, acc, 0, 0, 0);
            acc = __builtin_amdgcn_mfma_f32_16x16x32_bf16(Al[ct][1], xh1, acc, 0, 0, 0);
            // 4 independent top-2 chains (one per r)
#pragma unroll
            for (int r = 0; r < 4; ++r) {
                const float a  = acc[r];
                const int   k  = kb + ct * 16 + r;
                const float mn = fminf(a, bV[r]);
                const bool  c1 = a > bV[r];
                const int  mnk = c1 ? bK[r] : k;
                bV[r] = fmaxf(a, bV[r]);
                bK[r] = c1 ? k : bK[r];
                const bool c2_ = mn > sV[r];
                sV[r] = fmaxf(mn, sV[r]);
                sK[r] = c2_ ? mnk : sK[r];
            }
        }

        // merge 4 r-chains -> scalar top-2 (union-of-top2 merges)
        float b = bV[0], s = sV[0];
        int   bk = bK[0], sk = sK[0];
#pragma unroll
        for (int r = 1; r < 4; ++r) {
            const bool  c1 = bV[r] > b;
            const float nb  = c1 ? bV[r] : b;
            const int   nbk = c1 ? bK[r] : bk;
            const float mn  = c1 ? b : bV[r];
            const int   mnk = c1 ? bk : bK[r];
            const float so  = c1 ? sV[r] : s;     // 2nd of winning side
            const int   sok = c1 ? sK[r] : sk;
            const bool  c2_ = so > mn;
            s  = c2_ ? so : mn;
            sk = c2_ ? sok : mnk;
            b = nb; bk = nbk;
        }

        // butterfly over g (lanes ^16, ^32)
#pragma unroll
        for (int m = 16; m <= 32; m <<= 1) {
            const float ob  = __shfl_xor(b, m, 64);
            const int   obk = __shfl_xor(bk, m, 64);
            const float os  = __shfl_xor(s, m, 64);
            const int   osk = __shfl_xor(sk, m, 64);
            const bool  c1 = ob > b;
            const float nb  = c1 ? ob : b;
            const int   nbk = c1 ? obk : bk;
            const float mn  = c1 ? b : ob;
            const int   mnk = c1 ? bk : obk;
            const bool  c3 = os > s;
            const float ms  = c3 ? os : s;
            const int   msk = c3 ? osk : sk;
            const bool  c4 = mn > ms;
            s  = c4 ? mn : ms;
            sk = c4 ? mnk : msk;
            b = nb; bk = nbk;
        }
        if (g == 0) {
            const int row = t * 16 + col;
            cV1[w][row] = b;
            cV2[w][row] = s;
            cK [w][row] = (unsigned)bk | ((unsigned)sk << 16);
        }
    }
    __syncthreads();

    // ---- merge 8 waves' top-2 per row (2 threads/row + pair shfl), max ----
    {
        const int row = tid >> 1;
        const int h   = tid & 1;
        float b = -3.4e38f, s = -3.4e38f;
        int   bk = 0, sk = 0;
#pragma unroll
        for (int wv = 0; wv < 4; ++wv) {
            const int wj = h * 4 + wv;         // waves ascending => k ascending
            const unsigned ks = cK[wj][row];
            const float v1 = cV1[wj][row];
            const float v2 = cV2[wj][row];
            const int  k1 = (int)(ks & 0xFFFFu);
            const int  k2 = (int)(ks >> 16);
            {
                const bool c1 = v1 > b;
                const float mn = c1 ? b : v1;  const int mnk = c1 ? bk : k1;
                b  = c1 ? v1 : b;              bk  = c1 ? k1 : bk;
                const bool c2_ = mn > s;  s = c2_ ? mn : s;  sk = c2_ ? mnk : sk;
            }
            {
                const bool c1 = v2 > b;
                const float mn = c1 ? b : v2;  const int mnk = c1 ? bk : k2;
                b  = c1 ? v2 : b;              bk  = c1 ? k2 : bk;
                const bool c2_ = mn > s;  s = c2_ ? mn : s;  sk = c2_ ? mnk : sk;
            }
        }
        // combine halves (partner h=1 has strictly higher k's)
        const float ob  = __shfl_xor(b, 1, 64);
        const int   obk = __shfl_xor(bk, 1, 64);
        const float os  = __shfl_xor(s, 1, 64);
        const int   osk = __shfl_xor(sk, 1, 64);
        if (h == 0) {
            const bool  c1 = ob > b;           // tie keeps ours (lower k)
            const float nb  = c1 ? ob : b;
            const int   nbk = c1 ? obk : bk;
            const float mn  = c1 ? b : ob;
            const int   mnk = c1 ? bk : obk;
            const bool  c3 = os > s;
            const float ms  = c3 ? os : s;
            const int   msk = c3 ? osk : sk;
            const bool  c4 = mn > ms;
            const int   fsk = c4 ? mnk : msk;
            kws[row] = (unsigned)nbk | ((unsigned)fsk << 16);
        }
    }
    __syncthreads();

    // ---- exact recheck: 2 candidates/row on the reference grid ----
    {
        const int row = tid >> 1;
        const int ci  = tid & 1;
        const unsigned pr = kws[row];
        const int k = ci ? (int)(pr >> 16) : (int)(pr & 0xFFFFu);
        const float* cbr = codebook + (size_t)k * Dc;
        float a0 = 0.f, a1 = 0.f, a2 = 0.f, a3 = 0.f;
#pragma unroll
        for (int d4 = 0; d4 < 4; ++d4) {
            f32x4 cv0 = *(const f32x4*)(cbr + d4 * 16);
            f32x4 cv1 = *(const f32x4*)(cbr + d4 * 16 + 4);
            f32x4 cv2 = *(const f32x4*)(cbr + d4 * 16 + 8);
            f32x4 cv3 = *(const f32x4*)(cbr + d4 * 16 + 12);
            const float* xr = &xs[row][d4 * 16];
#pragma unroll
            for (int e = 0; e < 4; ++e) {
                a0 = __builtin_fmaf(xr[e],      cv0[e], a0);
                a1 = __builtin_fmaf(xr[4 + e],  cv1[e], a1);
                a2 = __builtin_fmaf(xr[8 + e],  cv2[e], a2);
                a3 = __builtin_fmaf(xr[12 + e], cv3[e], a3);
            }
        }
        const float a  = (a0 + a1) + (a2 + a3);
        const float d2 = __builtin_fmaf(-2.f, a, xs2[row]) + c2s[k];
        // d2 >= 0 -> float bits order-preserving as uint
        unsigned long long pk =
            ((unsigned long long)__float_as_uint(d2) << 32) | (unsigned)k;
        const unsigned long long o = __shfl_xor(pk, 1, 64);
        pk = o < pk ? o : pk;                  // min d2, ties -> lowest k
        if (ci == 0) {
            const int kwin = (int)(pk & 0x3FFu);
            kws[row] = (unsigned)kwin;
            out[OFF_IDX + (size_t)blockIdx.x * BLK_ROWS + row] = (float)kwin;
        }
    }
    __syncthreads();

    // ---- quantized write + loss: 2 threads/row, 32 channels each ----
    {
        const int row = tid & 255;
        const int cp  = tid >> 8;              // 0..1
        const int kw  = (int)kws[row];
        const float* cbw = codebook + (size_t)kw * Dc + cp * 32;
        float* qout = out + inBase + row;
        float ls = 0.f;
#pragma unroll
        for (int j = 0; j < 32; ++j) {
            const int c = cp * 32 + j;
            float qv = cbw[j];
            qout[(size_t)c * LHWc] = qv;       // coalesced across lanes per c
            float e = qv - xs[row][c];
            ls = __builtin_fmaf(e, e, ls);
        }
#pragma unroll
        for (int off = 32; off > 0; off >>= 1) ls += __shfl_down(ls, off, 64);
        if (lane == 0) atomicAdd(&out[OFF_LOSS], ls * (1.25f / (float)QSIZE));
    }
}

extern "C" void kernel_launch(void* const* d_in, const int* in_sizes, int n_in,
                              void* d_out, int out_size, void* d_ws, size_t ws_size,
                              hipStream_t stream) {
    const float* in = (const float*)d_in[0];   // [4,64,16,32,32] f32
    const float* cb = (const float*)d_in[1];   // [1024,64] f32
    float* out = (float*)d_out;
    (void)in_sizes; (void)n_in; (void)out_size; (void)d_ws; (void)ws_size;

    vq_zero<<<dim3(1), dim3(1), 0, stream>>>(out);
    vq_main<<<dim3(Nc / BLK_ROWS), dim3(512), 0, stream>>>(in, cb, out);
}

// Round 13
// 162.936 us; speedup vs baseline: 1.0119x; 1.0119x over previous
//
#include <hip/hip_runtime.h>

// (B,C,L,H,W) = (4,64,16,32,32), K=1024, D=C=64
constexpr int Cc   = 64;
constexpr int Kc   = 1024;
constexpr int Dc   = 64;
constexpr int LHWc = 16 * 32 * 32;        // 16384
constexpr int Nc   = 4 * LHWc;            // 65536 vectors
constexpr int QSIZE    = 4 * Cc * LHWc;   // 4194304
constexpr int OFF_LOSS = QSIZE;           // 4194304
constexpr int OFF_IDX  = QSIZE + 1;       // 4194305

constexpr int BLK_ROWS = 256;             // rows per block (16 MFMA tiles)
constexpr int NW       = 8;               // waves per block (512 threads)
constexpr int XPAD     = 68;              // r5's exact LDS layout

typedef __attribute__((ext_vector_type(8))) short short8;   // 8 x bf16 bits
typedef __attribute__((ext_vector_type(4))) float f32x4;

static __device__ __forceinline__ unsigned short f2bf(float f) {
    unsigned u = __float_as_uint(f);
    u += 0x7FFFu + ((u >> 16) & 1u);      // RNE (finite data only)
    return (unsigned short)(u >> 16);
}
static __device__ __forceinline__ float bf2f(unsigned short h) {
    return __uint_as_float(((unsigned)h) << 16);
}

// Prep: zero loss; codebook bf16 hi/lo split (coalesced); exact-chain c2 and
// c2n = -0.5*(c2+0.25) (MFMA accumulator seed; score = dot + c2n, maximize).
__global__ __launch_bounds__(256) void vq_prep(
    const float* __restrict__ cb, float* __restrict__ out,
    unsigned short* __restrict__ cbh, unsigned short* __restrict__ cbl,
    float* __restrict__ c2, float* __restrict__ c2n)
{
    const int t  = threadIdx.x;
    const int k0 = blockIdx.x * 64;
    if (blockIdx.x == 0 && t == 0) out[OFF_LOSS] = 0.0f;

    const int d  = t & 63;
#pragma unroll
    for (int r = 0; r < 16; ++r) {
        const int k = k0 + r * 4 + (t >> 6);
        const float v = cb[(size_t)k * Dc + d];
        unsigned short h = f2bf(v);
        cbh[(size_t)k * Dc + d] = h;
        cbl[(size_t)k * Dc + d] = f2bf(v - bf2f(h));
    }
    if (t < 64) {
        const int k = k0 + t;
        const float* c = cb + (size_t)k * Dc;
        float s = 0.f;
#pragma unroll
        for (int dd = 0; dd < Dc; ++dd) s = __builtin_fmaf(c[dd], c[dd], s);
        c2[k]  = s;
        c2n[k] = -0.5f * (s + 0.25f);
    }
}

// r5's proven shape (8 waves x 128 codes in regs / 256 rows / 16 1-tile
// iters / grid 256) with register-NEGATIVE tweaks only (512-thread blocks
// are hard-capped at 128 VGPR by the allocator; r5's 120 fit, r11/r12's
// >=128 serialized or spilled):
//  - acc seeded from LDS c2n per ct (wave-uniform broadcast read): deletes
//    c2r[8][4] (-32 VGPR) and the 2-VALU/candidate score math.
//  - no merge phase: recheck all 16 wave-local top-2 candidates per row on
//    the REFERENCE GRID d2 = fl(fma(-2,a,x2)+c2), f32-bit compare, lowest-k
//    ties (r10 lesson: d2's k-part is quantized to ulp(x2+c2~64)=7.6e-6;
//    ~0.2% of rows coarse-tie and the reference argmin resolves by low k;
//    the fine in-loop proxy is ONLY a candidate generator).
__global__ __launch_bounds__(512, 2) void vq_main(
    const float* __restrict__ in, const float* __restrict__ codebook,
    const unsigned short* __restrict__ cbh,
    const unsigned short* __restrict__ cbl,
    const float* __restrict__ c2g, const float* __restrict__ c2ng,
    float* __restrict__ out)
{
    __shared__ float    xs[BLK_ROWS][XPAD];    // 69632 B
    __shared__ short8   xfh[2048];             // 32768 B: X frags hi
    __shared__ short8   xfl[2048];             // 32768 B: X frags lo
    __shared__ float    c2ns[Kc];              //  4096 B: acc seeds
    __shared__ float    xs2[BLK_ROWS];         //  1024 B
    __shared__ unsigned cK[NW][BLK_ROWS];      //  8192 B: per-wave bK|sK<<16
    __shared__ unsigned kws[BLK_ROWS];         //  1024 B  (total 149504 B)

    const int tid  = threadIdx.x;
    const int lane = tid & 63;
    const int w    = __builtin_amdgcn_readfirstlane(tid >> 6);  // 0..7
    const int col  = lane & 15;
    const int g    = lane >> 4;

    const int bq = blockIdx.x >> 6;                    // batch (64 blk/batch)
    const int p0 = (blockIdx.x & 63) * BLK_ROWS;       // LHW offset
    const size_t inBase = (size_t)bq * (Cc * LHWc) + p0;

    // ---- stage seeds + X[256 rows][64 d] into LDS (coalesced) ----
    c2ns[tid]       = c2ng[tid];
    c2ns[tid + 512] = c2ng[tid + 512];
#pragma unroll
    for (int i = 0; i < 32; ++i) {
        int idx = i * 512 + tid;
        int d = idx >> 8, row = idx & 255;
        xs[row][d] = in[inBase + (size_t)d * LHWc + row];
    }
    __syncthreads();

    // ---- x2 per row: exact ascending fma chain (recheck only) ----
    if (tid < BLK_ROWS) {
        float s = 0.f;
#pragma unroll
        for (int d = 0; d < Dc; ++d) s = __builtin_fmaf(xs[tid][d], xs[tid][d], s);
        xs2[tid] = s;
    }

    // ---- X fragments (bf16 hi/lo) from xs -> LDS ----
#pragma unroll
    for (int j = 0; j < 4; ++j) {
        const int c  = tid + j * 512;          // chunk = t*128 + kt*64 + g*16 + cl
        const int t  = c >> 7;
        const int kt = (c >> 6) & 1;
        const int l  = c & 63;
        const int row = t * 16 + (l & 15);
        const int d0  = kt * 32 + (l >> 4) * 8;
        f32x4 v0 = *(const f32x4*)&xs[row][d0];
        f32x4 v1 = *(const f32x4*)&xs[row][d0 + 4];
        short8 h8, l8;
#pragma unroll
        for (int e = 0; e < 4; ++e) {
            unsigned short ha = f2bf(v0[e]);
            h8[e]     = (short)ha;
            l8[e]     = (short)f2bf(v0[e] - bf2f(ha));
            unsigned short hb = f2bf(v1[e]);
            h8[4 + e] = (short)hb;
            l8[4 + e] = (short)f2bf(v1[e] - bf2f(hb));
        }
        xfh[c] = h8; xfl[c] = l8;
    }

    // ---- this wave's 128 codes as A-fragments (loaded ONCE) ----
    short8 Ah[8][2], Al[8][2];
#pragma unroll
    for (int ct = 0; ct < 8; ++ct) {
        const size_t cb0 = (size_t)(w * 128 + ct * 16 + col) * Dc + g * 8;
#pragma unroll
        for (int kt = 0; kt < 2; ++kt) {
            Ah[ct][kt] = *(const short8*)(cbh + cb0 + kt * 32);
            Al[ct][kt] = *(const short8*)(cbl + cb0 + kt * 32);
        }
    }
    __syncthreads();

    const int kb = w * 128 + g * 4;            // + ct*16 + r at use

    // ---- main loop: 16 X-tiles, codes stay in registers ----
#pragma unroll 1
    for (int t = 0; t < 16; ++t) {
        const short8 xh0 = xfh[t * 128 + lane];
        const short8 xh1 = xfh[t * 128 + 64 + lane];
        const short8 xl0 = xfl[t * 128 + lane];
        const short8 xl1 = xfl[t * 128 + 64 + lane];

        float bV = -3.4e38f, sV = -3.4e38f;    // MAXIMIZE score = dot + c2n
        int   bK = 0, sK = 0;

#pragma unroll
        for (int ct = 0; ct < 8; ++ct) {
            // seed: wave-uniform per g-group LDS broadcast (conflict-free)
            f32x4 acc = *(const f32x4*)&c2ns[w * 128 + ct * 16 + g * 4];
            // split-3 dot: hh + hl + lh (ll ~1e-10, covered by exact recheck)
            acc = __builtin_amdgcn_mfma_f32_16x16x32_bf16(Ah[ct][0], xh0, acc, 0, 0, 0);
            acc = __builtin_amdgcn_mfma_f32_16x16x32_bf16(Ah[ct][1], xh1, acc, 0, 0, 0);
            acc = __builtin_amdgcn_mfma_f32_16x16x32_bf16(Ah[ct][0], xl0, acc, 0, 0, 0);
            acc = __builtin_amdgcn_mfma_f32_16x16x32_bf16(Ah[ct][1], xl1, acc, 0, 0, 0);
            acc = __builtin_amdgcn_mfma_f32_16x16x32_bf16(Al[ct][0], xh0, acc, 0, 0, 0);
            acc = __builtin_amdgcn_mfma_f32_16x16x32_bf16(Al[ct][1], xh1, acc, 0, 0, 0);
#pragma unroll
            for (int r = 0; r < 4; ++r) {
                const float a = acc[r];
                const int   k = kb + ct * 16 + r;
                const bool  c1 = a > bV;
                const float nb  = c1 ? a : bV;
                const int   nbk = c1 ? k : bK;
                const float mn  = c1 ? bV : a;
                const int   mnk = c1 ? bK : k;
                const bool  c2_ = mn > sV;
                sV = c2_ ? mn : sV;
                sK = c2_ ? mnk : sK;
                bV = nb; bK = nbk;
            }
        }

        // butterfly over g (lanes ^16, ^32): top-2 of wave's 128 codes per row
#pragma unroll
        for (int m = 16; m <= 32; m <<= 1) {
            const float ob  = __shfl_xor(bV, m, 64);
            const int   obk = __shfl_xor(bK, m, 64);
            const float os  = __shfl_xor(sV, m, 64);
            const int   osk = __shfl_xor(sK, m, 64);
            const bool  c1 = ob > bV;
            const float nb  = c1 ? ob : bV;
            const int   nbk = c1 ? obk : bK;
            const float mn  = c1 ? bV : ob;
            const int   mnk = c1 ? bK : obk;
            const bool  c3 = os > sV;
            const float ms  = c3 ? os : sV;
            const int   msk = c3 ? osk : sK;
            const bool  c4 = mn > ms;
            sV = c4 ? mn : ms;
            sK = c4 ? mnk : msk;
            bV = nb; bK = nbk;
        }
        if (g == 0) {
            cK[w][t * 16 + col] = (unsigned)bK | ((unsigned)sK << 16);
        }
    }
    __syncthreads();

    // ---- exact recheck of ALL 16 wave-local top-2 candidates per row ----
    // Reference-grid scoring (r11-proven): d2 = fl(fma(-2,a,x2) + c2),
    // f32-bit compare, lowest-k ties.
    {
        const int row = tid >> 1;
        const int h   = tid & 1;               // handles waves h*4 .. h*4+3
        float x[64];
#pragma unroll
        for (int d4 = 0; d4 < 16; ++d4) {
            f32x4 xv = *(const f32x4*)&xs[row][d4 * 4];
            x[d4 * 4 + 0] = xv[0]; x[d4 * 4 + 1] = xv[1];
            x[d4 * 4 + 2] = xv[2]; x[d4 * 4 + 3] = xv[3];
        }
        const float x2 = xs2[row];

        unsigned long long best = ~0ull;
#pragma unroll
        for (int wv = 0; wv < 4; ++wv) {
            const unsigned ks = cK[h * 4 + wv][row];
#pragma unroll
            for (int ci = 0; ci < 2; ++ci) {
                const int k = ci ? (int)(ks >> 16) : (int)(ks & 0xFFFFu);
                const float* cbr = codebook + (size_t)k * Dc;
                float a0 = 0.f, a1 = 0.f, a2 = 0.f, a3 = 0.f;
#pragma unroll
                for (int d = 0; d < 64; d += 4) {
                    a0 = __builtin_fmaf(x[d + 0], cbr[d + 0], a0);
                    a1 = __builtin_fmaf(x[d + 1], cbr[d + 1], a1);
                    a2 = __builtin_fmaf(x[d + 2], cbr[d + 2], a2);
                    a3 = __builtin_fmaf(x[d + 3], cbr[d + 3], a3);
                }
                const float a  = (a0 + a1) + (a2 + a3);
                const float d2 = __builtin_fmaf(-2.f, a, x2) + c2g[k];
                // d2 >= 0 -> float bits order-preserving as uint
                unsigned long long pk =
                    ((unsigned long long)__float_as_uint(d2) << 32) | (unsigned)k;
                best = pk < best ? pk : best;  // min d2, ties -> lowest k
            }
        }
        const unsigned long long o = __shfl_xor(best, 1, 64);
        best = o < best ? o : best;
        if (h == 0) {
            const int kwin = (int)(best & 0x3FFu);
            kws[row] = (unsigned)kwin;
            out[OFF_IDX + (size_t)blockIdx.x * BLK_ROWS + row] = (float)kwin;
        }
    }
    __syncthreads();

    // ---- quantized write + loss: 2 threads/row, 32 channels each ----
    {
        const int row = tid & 255;
        const int cp  = tid >> 8;              // 0..1
        const int kw  = (int)kws[row];
        const float* cbw = codebook + (size_t)kw * Dc + cp * 32;
        float* qout = out + inBase + row;
        float ls = 0.f;
#pragma unroll
        for (int j = 0; j < 32; ++j) {
            const int c = cp * 32 + j;
            float qv = cbw[j];
            qout[(size_t)c * LHWc] = qv;       // coalesced across lanes per c
            float e = qv - xs[row][c];
            ls = __builtin_fmaf(e, e, ls);
        }
#pragma unroll
        for (int off = 32; off > 0; off >>= 1) ls += __shfl_down(ls, off, 64);
        if (lane == 0) atomicAdd(&out[OFF_LOSS], ls * (1.25f / (float)QSIZE));
    }
}

extern "C" void kernel_launch(void* const* d_in, const int* in_sizes, int n_in,
                              void* d_out, int out_size, void* d_ws, size_t ws_size,
                              hipStream_t stream) {
    const float* in = (const float*)d_in[0];   // [4,64,16,32,32] f32
    const float* cb = (const float*)d_in[1];   // [1024,64] f32
    float* out = (float*)d_out;
    (void)in_sizes; (void)n_in; (void)out_size; (void)ws_size;

    unsigned short* cbh = (unsigned short*)d_ws;                 // 128 KB
    unsigned short* cbl = cbh + (size_t)Kc * Dc;                 // 128 KB
    float*          c2  = (float*)(cbl + (size_t)Kc * Dc);       // 4 KB
    float*          c2n = c2 + Kc;                               // 4 KB

    vq_prep<<<dim3(16), dim3(256), 0, stream>>>(cb, out, cbh, cbl, c2, c2n);
    vq_main<<<dim3(Nc / BLK_ROWS), dim3(512), 0, stream>>>(in, cb, cbh, cbl, c2, c2n, out);
}